// Round 17
// baseline (638.240 us; speedup 1.0000x reference)
//
#include <hip/hip_runtime.h>
#include <stdint.h>

typedef __attribute__((ext_vector_type(8))) __bf16 bf16x8;
typedef __attribute__((ext_vector_type(4))) float f32x4;
typedef __attribute__((ext_vector_type(2))) long long2v;
typedef unsigned short u16;
typedef unsigned char u8;

#define DEV static __device__ __forceinline__

constexpr int NB = 8;           // batch
constexpr int AA = 2784;        // anchors
constexpr int AM1 = 2783;       // A-1
constexpr int DD = 1408;        // D = 64*22
constexpr int MT = NB * AA;     // 22272 total rows (= 174*128 exactly)
constexpr int MH = MT / 2;      // first-half rows (f32 attn fused in softmax)
constexpr int KP = 2816;        // padded K / attP row stride (mult of 128)

DEV u16 f2bf(float f) {
  uint32_t u = __builtin_bit_cast(uint32_t, f);
  u += 0x7FFFu + ((u >> 16) & 1u);
  return (u16)(u >> 16);
}
DEV float bf2f(unsigned v) { return __builtin_bit_cast(float, v << 16); }
DEV u8 f2f8(float f) {
  return (u8)(__builtin_amdgcn_cvt_pk_fp8_f32(f, f, 0, false) & 0xff);
}
DEV float4 cv4(unsigned w) {
  float4 r;
  r.x = __builtin_amdgcn_cvt_f32_fp8((int)w, 0);
  r.y = __builtin_amdgcn_cvt_f32_fp8((int)w, 1);
  r.z = __builtin_amdgcn_cvt_f32_fp8((int)w, 2);
  r.w = __builtin_amdgcn_cvt_f32_fp8((int)w, 3);
  return r;
}
DEV unsigned pk4(float a, float b, float c, float d) {
  int r = __builtin_amdgcn_cvt_pk_fp8_f32(a, b, 0, false);
  r = __builtin_amdgcn_cvt_pk_fp8_f32(c, d, r, true);
  return (unsigned)r;
}

// async global->LDS, 16B per lane. LDS dest is wave-uniform base + lane*16 by HW.
DEV void load16_lds(const void* g, void* l) {
  auto gp = (const __attribute__((address_space(1))) uint32_t*)(uintptr_t)g;
  auto lp = (__attribute__((address_space(3))) uint32_t*)(uint32_t)(uintptr_t)l;
  __builtin_amdgcn_global_load_lds(gp, lp, 16, 0, 0);
}

#define VMW(n) asm volatile("s_waitcnt vmcnt(" #n ")" ::: "memory")
#define VMW0 asm volatile("s_waitcnt vmcnt(0)" ::: "memory")
#define LGK(n) asm volatile("s_waitcnt lgkmcnt(" #n ")" ::: "memory")
#define BARR asm volatile("s_barrier" ::: "memory")
#define SCHB __builtin_amdgcn_sched_barrier(0)

// 16 fp8 MFMAs: 4 m-frags x 2 n-frags x 2 k-slots
DEV void mf16c(f32x4 (&acc)[4][2], const long (&a)[4][2], const long (&b)[2][2]) {
  __builtin_amdgcn_s_setprio(1);
#pragma unroll
  for (int mt = 0; mt < 4; ++mt)
#pragma unroll
    for (int nt = 0; nt < 2; ++nt)
#pragma unroll
      for (int ks = 0; ks < 2; ++ks)
        acc[mt][nt] = __builtin_amdgcn_mfma_f32_16x16x32_fp8_fp8(
            a[mt][ks], b[nt][ks], acc[mt][nt], 0, 0, 0);
  __builtin_amdgcn_s_setprio(0);
}

// ------- unified fp8 GEMM: 128x128 tile, 2x4 waves (64x32), BK=64, 4 blocks/CU -------
// 32KB LDS/block -> 4 independent barrier groups per CU cover each other's stalls.
// MODE 1: scores = baf8 @ attwt8^T, K=1408 -> scattered fp8 (+bias) into attP8[.][KP]
// MODE 2: att_feat = attP8 @ baft8^T (per batch z), K=2816 -> bf16 out (x1/256)
template <int MODE>
__global__ __launch_bounds__(512, 8) void gemm_k(const u8* __restrict__ A,
                                                 const u8* __restrict__ Bt,
                                                 u8* __restrict__ out8,
                                                 u16* __restrict__ outh,
                                                 const float* __restrict__ bias1) {
  constexpr int K   = (MODE == 1) ? 1408 : KP;
  constexpr int NT  = K / 64;
  constexpr int LDA = (MODE == 1) ? 1408 : KP;
  constexpr int LDB = (MODE == 1) ? 1408 : KP;
  constexpr int MR  = (MODE == 1) ? MT : AA;     // valid A rows
  constexpr int NRB = (MODE == 1) ? KP : 1408;   // valid B rows
  __shared__ __align__(16) u8 As8[2][8192];      // 128 x 64
  __shared__ __align__(16) u8 Bs8[2][8192];      // 128 x 64
  const int tid = threadIdx.x;
  const int lane = tid & 63;
  const int w = tid >> 6;
  const int wr = w >> 2, wc = w & 3;             // wave tile 64 x 32
  const int l16 = lane & 15, lq = lane >> 4;

  // T1 bijective XCD swizzle, y-fastest within chunk
  const int gx = gridDim.x, gy = gridDim.y;
  const int nwg = gx * gy;
  const int i = blockIdx.x + blockIdx.y * gx;
  const int xcd = i & 7, pos = i >> 3;
  const int q = nwg >> 3, r = nwg & 7;
  const int lid = (xcd < r ? xcd * (q + 1) : r * (q + 1) + (xcd - r) * q) + pos;
  const int m0 = (lid / gy) * 128, n0 = (lid % gy) * 128;

  const u8* Ab = A;
  const u8* Bb = Bt;
  u16* outp = outh;
  if constexpr (MODE == 2) {
    const int bz = blockIdx.z;
    Ab += (size_t)bz * AA * KP;
    Bb += (size_t)bz * DD * KP;
    outp += (size_t)bz * AA * DD;
  }

  // stage one 128x64 tile: 1 inst/thread; source col pre-swizzled (involution)
  auto stA = [&](int buf, int kt) {
    int c = tid;
    int row = c >> 2, sl = c & 3;
    int sr = m0 + row;
    sr = sr < MR - 1 ? sr : MR - 1;
    load16_lds(Ab + (size_t)sr * LDA + kt * 64 + ((sl ^ ((row >> 1) & 3)) << 4),
               &As8[buf][c << 4]);
  };
  auto stB = [&](int buf, int kt) {
    int c = tid;
    int row = c >> 2, sl = c & 3;
    int sr = n0 + row;
    sr = sr < NRB - 1 ? sr : NRB - 1;
    load16_lds(Bb + (size_t)sr * LDB + kt * 64 + ((sl ^ ((row >> 1) & 3)) << 4),
               &Bs8[buf][c << 4]);
  };
  // b128 fragment reads; unit lq^((row>>1)&3) undoes staging swizzle -> canonical
  // chunk lq; lo/hi 8B feed the two K=32 MFMAs (A/B k-permutation cancels).
  auto rdA = [&](int buf, long (&a)[4][2]) {
#pragma unroll
    for (int mt = 0; mt < 4; ++mt) {
      int rloc = wr * 64 + mt * 16 + l16;
      int u = lq ^ ((rloc >> 1) & 3);
      long2v v = *(const long2v*)&As8[buf][rloc * 64 + u * 16];
      a[mt][0] = v[0]; a[mt][1] = v[1];
    }
  };
  auto rdB = [&](int buf, long (&b)[2][2]) {
#pragma unroll
    for (int nt = 0; nt < 2; ++nt) {
      int R = wc * 32 + nt * 16 + l16;
      int u = lq ^ ((R >> 1) & 3);
      long2v v = *(const long2v*)&Bs8[buf][R * 64 + u * 16];
      b[nt][0] = v[0]; b[nt][1] = v[1];
    }
  };

  f32x4 acc[4][2];
#pragma unroll
  for (int i2 = 0; i2 < 4; ++i2)
#pragma unroll
    for (int j = 0; j < 2; ++j) acc[i2][j] = 0.f;

  long a[4][2], b[2][2];

  // prologue: buf0 <- t0, buf1 <- t1; wait buf0 (buf1's 2 insts in flight)
  stA(0, 0); stB(0, 0);
  stA(1, 1); stB(1, 1);
  VMW(2);
  BARR;

  for (int t = 0; t < NT; ++t) {
    const int cur = t & 1, nxt = cur ^ 1;
    // stage t+1 into the buffer whose reads finished at t-1's barrier
    if (t + 1 < NT) { stA(nxt, t + 1); stB(nxt, t + 1); }
    rdA(cur, a); rdB(cur, b);
    LGK(0); SCHB;
    mf16c(acc, a, b);                  // 16 MFMA
    if (t + 1 < NT) { VMW0; BARR; }    // 4 blocks/CU cover this drain
  }

  // ---- epilogue ----  C/D map: col = lane&15, row = (lane>>4)*4 + reg
  if constexpr (MODE == 1) {
#pragma unroll
    for (int mi = 0; mi < 4; ++mi)
#pragma unroll
      for (int r2 = 0; r2 < 4; ++r2) {
        int m = m0 + wr * 64 + mi * 16 + lq * 4 + r2;   // < MT (174*128 exact)
        int ii = m % AA;
#pragma unroll
        for (int ni = 0; ni < 2; ++ni) {
          int n = n0 + wc * 32 + ni * 16 + l16;
          if (n >= AM1) continue;
          int col = n + (n >= ii);                 // scatter: skip diagonal
          out8[(size_t)m * KP + col] = f2f8(acc[mi][ni][r2] + bias1[n]);
        }
      }
  } else {
#pragma unroll
    for (int mi = 0; mi < 4; ++mi)
#pragma unroll
      for (int r2 = 0; r2 < 4; ++r2) {
        int m = m0 + wr * 64 + mi * 16 + lq * 4 + r2;
        if (m >= AA) continue;
        size_t base = (size_t)m * DD;
#pragma unroll
        for (int ni = 0; ni < 2; ++ni) {
          int n = n0 + wc * 32 + ni * 16 + l16;
          outp[base + n] = f2bf(acc[mi][ni][r2] * 0.00390625f);
        }
      }
  }
}

// ---------------- 1x1 conv: feats[b][o][h][w] ----------------
__global__ __launch_bounds__(256) void conv_k(const float* __restrict__ x,
                                              const float* __restrict__ w,
                                              const float* __restrict__ bias,
                                              float* __restrict__ feats) {
  __shared__ float xs[256 * 40];
  int bb = blockIdx.x / 22, h = blockIdx.x % 22;
  const float* xp = x + (size_t)bb * 256 * 880 + h * 40;
  for (int l = threadIdx.x; l < 256 * 40; l += 256)
    xs[l] = xp[(l / 40) * 880 + (l % 40)];
  __syncthreads();
  for (int l = threadIdx.x; l < 64 * 40; l += 256) {
    int o = l / 40, ww = l % 40;
    float acc = bias[o];
    const float* wr = w + o * 256;
#pragma unroll 8
    for (int c = 0; c < 256; ++c) acc += xs[c * 40 + ww] * wr[c];
    feats[((size_t)(bb * 64 + o) * 22 + h) * 40 + ww] = acc;
  }
}

// ---------------- fused gather+mask -> baf bf16, baf8 fp8, baft8 fp8^T ----------------
__global__ __launch_bounds__(256) void gt_k(const float* __restrict__ feats,
                                            const int* __restrict__ cut,
                                            const u8* __restrict__ inv,
                                            u16* __restrict__ baf,
                                            u8* __restrict__ baf8,
                                            u8* __restrict__ bft8) {
  unsigned probe = 0;
#pragma unroll
  for (int t = 0; t < 10; ++t)
    probe |= (unsigned)inv[4 * t + 1] | (unsigned)inv[4 * t + 2] | (unsigned)inv[4 * t + 3];
  const bool is_u8 = (probe != 0);  // i32 storage -> high bytes all zero
  __shared__ u8 t8[64][65];
  int a0 = blockIdx.x * 64, d0 = blockIdx.y * 64, b = blockIdx.z;
  int tx = threadIdx.x & 63, ty = threadIdx.x >> 6;
  int d = d0 + tx, o = d / 22, h = d - o * 22;
  for (int r = ty; r < 64; r += 4) {
    int a = a0 + r;
    u8 f8 = 0;
    if (a < AA) {
      int msk = is_u8 ? (int)inv[a * 22 + h] : ((const int*)inv)[a * 22 + h];
      float v = 0.f;
      if (!msk) v = feats[((size_t)(b * 64 + o) * 22 + h) * 40 + cut[a * 22 + h]];
      baf[((size_t)b * AA + a) * DD + d] = f2bf(v);
      f8 = f2f8(v);
      baf8[((size_t)b * AA + a) * DD + d] = f8;
    }
    t8[r][tx] = f8;
  }
  __syncthreads();
  for (int r = ty; r < 64; r += 4) {
    int a = a0 + tx;
    if (a < AA) bft8[((size_t)b * DD + d0 + r) * KP + a] = t8[tx][r];
  }
}

// ---------------- attn_w (1408,2783) f32 -> attwt8 (2816,1408) fp8, zero pad ----------------
__global__ __launch_bounds__(256) void tr_attw_k(const float* __restrict__ w,
                                                 u8* __restrict__ wt8) {
  __shared__ u8 t8[64][65];
  int n0 = blockIdx.x * 64, k0 = blockIdx.y * 64;
  int tx = threadIdx.x & 63, ty = threadIdx.x >> 6;
  for (int r = ty; r < 64; r += 4) {
    int n = n0 + tx;
    t8[r][tx] = (n < AM1) ? f2f8(w[(size_t)(k0 + r) * AM1 + n]) : (u8)0;
  }
  __syncthreads();
  for (int r = ty; r < 64; r += 4)
    wt8[(size_t)(n0 + r) * 1408 + k0 + tx] = t8[tx][r];
}

// ---------------- pack head weights bf16: wt[n][k], n<2 cls, 2..145 reg, pad->160 ----------------
__global__ __launch_bounds__(256) void wt_k(const float* __restrict__ cw,
                                            const float* __restrict__ rw,
                                            u16* __restrict__ wt) {
  int n = blockIdx.x;
  for (int k = threadIdx.x; k < 2816; k += 256) {
    float v = 0.f;
    if (n < 2) v = cw[(size_t)k * 2 + n];
    else if (n < 146) v = rw[(size_t)k * 144 + (n - 2)];
    wt[(size_t)n * 2816 + k] = f2bf(v);
  }
}

// ---------------- fp8 row softmax in place; out = attn*256 fp8; rows<MH also write f32 ----------------
__global__ __launch_bounds__(256) void softf_k(u8* __restrict__ attP,
                                               float* __restrict__ fdst) {
  const int row = blockIdx.x;            // 0..MT-1
  const int i = row % AA;
  u8* p = attP + (size_t)row * KP;
  const int t = threadIdx.x;
  const bool act = (t < 176);            // 176 uint4 chunks of 16 fp8
  uint4 qw = act ? ((const uint4*)p)[t] : make_uint4(0, 0, 0, 0);
  float v[16];
  { float4 f = cv4(qw.x); v[0] = f.x; v[1] = f.y; v[2] = f.z; v[3] = f.w; }
  { float4 f = cv4(qw.y); v[4] = f.x; v[5] = f.y; v[6] = f.z; v[7] = f.w; }
  { float4 f = cv4(qw.z); v[8] = f.x; v[9] = f.y; v[10] = f.z; v[11] = f.w; }
  { float4 f = cv4(qw.w); v[12] = f.x; v[13] = f.y; v[14] = f.z; v[15] = f.w; }
  const int base = t * 16;
  float mx = -3e38f;
#pragma unroll
  for (int e = 0; e < 16; ++e) {
    int j = base + e;
    if (act && j < AA && j != i) mx = fmaxf(mx, v[e]);
  }
#pragma unroll
  for (int o = 1; o < 64; o <<= 1) mx = fmaxf(mx, __shfl_xor(mx, o));
  __shared__ float rm[4], rs[4];
  if (!(t & 63)) rm[t >> 6] = mx;
  __syncthreads();
  mx = fmaxf(fmaxf(rm[0], rm[1]), fmaxf(rm[2], rm[3]));
  float s = 0.f, ev[16];
#pragma unroll
  for (int e = 0; e < 16; ++e) {
    int j = base + e;
    float tv = (act && j < AA && j != i) ? __expf(v[e] - mx) : 0.f;
    ev[e] = tv; s += tv;
  }
#pragma unroll
  for (int o = 1; o < 64; o <<= 1) s += __shfl_xor(s, o);
  if (!(t & 63)) rs[t >> 6] = s;
  __syncthreads();
  s = (rs[0] + rs[1]) + (rs[2] + rs[3]);
  const float inv = 1.f / s;
#pragma unroll
  for (int e = 0; e < 16; ++e) ev[e] *= inv;
  if (act) {
    const float sc = 256.f;
    uint4 ow;
    ow.x = pk4(ev[0] * sc, ev[1] * sc, ev[2] * sc, ev[3] * sc);
    ow.y = pk4(ev[4] * sc, ev[5] * sc, ev[6] * sc, ev[7] * sc);
    ow.z = pk4(ev[8] * sc, ev[9] * sc, ev[10] * sc, ev[11] * sc);
    ow.w = pk4(ev[12] * sc, ev[13] * sc, ev[14] * sc, ev[15] * sc);
    ((uint4*)p)[t] = ow;
    // rows < MH: write f32 attn directly (region disjoint from attf park)
    if (row < MH && t < 174) {
      float4* dp = (float4*)(fdst + (size_t)row * AA + base);
      dp[0] = make_float4(ev[0], ev[1], ev[2], ev[3]);
      dp[1] = make_float4(ev[4], ev[5], ev[6], ev[7]);
      dp[2] = make_float4(ev[8], ev[9], ev[10], ev[11]);
      dp[3] = make_float4(ev[12], ev[13], ev[14], ev[15]);
    }
  }
}

// ---------------- fp8*256 (stride KP) -> f32 (stride AA) expand ----------------
__global__ __launch_bounds__(256) void exp_k(const u8* __restrict__ src,
                                             float* __restrict__ dst) {
  int row = blockIdx.x;
  int t = threadIdx.x;
  if (t >= 174) return;
  uint4 qw = ((const uint4*)(src + (size_t)row * KP))[t];
  const float is = 0.00390625f;
  float4 f0 = cv4(qw.x), f1 = cv4(qw.y), f2 = cv4(qw.z), f3 = cv4(qw.w);
  float4* dp = (float4*)(dst + (size_t)row * AA + t * 16);
  dp[0] = make_float4(f0.x * is, f0.y * is, f0.z * is, f0.w * is);
  dp[1] = make_float4(f1.x * is, f1.y * is, f1.z * is, f1.w * is);
  dp[2] = make_float4(f2.x * is, f2.y * is, f2.z * is, f2.w * is);
  dp[3] = make_float4(f3.x * is, f3.y * is, f3.z * is, f3.w * is);
}

// ---------------- head GEMM (bf16, depth-2 counted-vmcnt, BN=160): [attf|baf] @ wt^T ----------------
__global__ __launch_bounds__(256) void head_k(const u16* __restrict__ A1,
                                              const u16* __restrict__ A2,
                                              const u16* __restrict__ Bt,
                                              float* __restrict__ outf,
                                              const float* __restrict__ b1,
                                              const float* __restrict__ b2,
                                              const float* __restrict__ anch) {
  constexpr int K = 2816, NT = K / 32, BN = 160, HN = 80, NF = 5;
  __shared__ __align__(16) u16 As[2][128 * 32];
  __shared__ __align__(16) u16 Bs[2][BN * 32 + 512];   // +1KB pad for clamped overhang
  const int tid = threadIdx.x;
  const int lane = tid & 63;
  const int wm = tid >> 7, wn = (tid >> 6) & 1;
  const int m0 = blockIdx.x * 128;
  const int l16 = lane & 15, lq = lane >> 4;

  // uniform 5 load insts per thread (2 A + 3 B with clamped overhang)
  auto stage = [&](int buf, int t) {
    const int k0 = t * 32;
    const u16* Asrc = (k0 < 1408) ? A1 : A2;
    const int kk = (k0 < 1408) ? k0 : k0 - 1408;
#pragma unroll
    for (int inst = 0; inst < 2; ++inst) {
      int c = tid + inst * 256;
      load16_lds(Asrc + (size_t)(m0 + (c >> 2)) * 1408 + kk + (c & 3) * 8, &As[buf][c * 8]);
    }
#pragma unroll
    for (int inst = 0; inst < 3; ++inst) {
      int c = tid + inst * 256;
      int ce = c < BN * 4 ? c : BN * 4 - 1;
      load16_lds(Bt + (size_t)(ce >> 2) * K + k0 + (ce & 3) * 8, &Bs[buf][ce * 8]);
    }
  };

  f32x4 acc[4][NF];
#pragma unroll
  for (int i = 0; i < 4; ++i)
#pragma unroll
    for (int j = 0; j < NF; ++j) acc[i][j] = 0.f;

  stage(0, 0);
  stage(1, 1);
  for (int t = 0; t < NT; ++t) {
    if (t + 1 < NT) VMW(5); else VMW0;
    BARR;
    const int cur = t & 1;
    bf16x8 av[4], bv[NF];
#pragma unroll
    for (int mt = 0; mt < 4; ++mt)
      av[mt] = *(const bf16x8*)&As[cur][(wm * 64 + mt * 16 + l16) * 32 + lq * 8];
#pragma unroll
    for (int nt = 0; nt < NF; ++nt)
      bv[nt] = *(const bf16x8*)&Bs[cur][(wn * HN + nt * 16 + l16) * 32 + lq * 8];
#pragma unroll
    for (int mt = 0; mt < 4; ++mt)
#pragma unroll
      for (int nt = 0; nt < NF; ++nt)
        acc[mt][nt] = __builtin_amdgcn_mfma_f32_16x16x32_bf16(av[mt], bv[nt], acc[mt][nt], 0, 0, 0);
    BARR;                                 // all waves done reading buf cur
    if (t + 2 < NT) stage(cur, t + 2);
  }

#pragma unroll
  for (int nt = 0; nt < NF; ++nt) {
    int n = wn * HN + nt * 16 + l16;
    if (n >= 146) continue;
#pragma unroll
    for (int mt = 0; mt < 4; ++mt)
#pragma unroll
      for (int r = 0; r < 4; ++r) {
        int m = m0 + wm * 64 + mt * 16 + lq * 4 + r;
        int ii = m % AA;
        float v = acc[mt][nt][r];
        if (n < 2) {
          outf[(size_t)m * 148 + n] = v + b1[n];
          if (n == 0) {
            outf[(size_t)m * 148 + 2] = anch[ii * 148 + 2];
            outf[(size_t)m * 148 + 3] = anch[ii * 148 + 3];
          }
        } else {
          int rr = n - 2;
          v += b2[rr];
          if (rr >= 72) v = 1.f / (1.f + __expf(-v));
          outf[(size_t)m * 148 + 4 + rr] = anch[ii * 148 + 4 + rr] + v;
        }
      }
  }
}

extern "C" void kernel_launch(void* const* d_in, const int* in_sizes, int n_in,
                              void* d_out, int out_size, void* d_ws, size_t ws_size,
                              hipStream_t stream) {
  const float* x       = (const float*)d_in[0];
  const float* conv_w  = (const float*)d_in[1];
  const float* conv_b  = (const float*)d_in[2];
  const float* attn_w  = (const float*)d_in[3];
  const float* attn_b  = (const float*)d_in[4];
  const float* cls_w   = (const float*)d_in[5];
  const float* cls_b   = (const float*)d_in[6];
  const float* reg_w   = (const float*)d_in[7];
  const float* reg_b   = (const float*)d_in[8];
  const float* anchors = (const float*)d_in[9];
  const int*   cut_xs  = (const int*)d_in[10];
  const u8*    inv     = (const u8*)d_in[11];

  float* props = (float*)d_out;
  float* attn  = props + (size_t)MT * 148;   // f32 attn_mat out (248 MB)
  // attf (62.7 MB) parks in the SECOND half of attn [MH rows onward]; softmax
  // writes f32 rows < MH directly (disjoint); exp_k finishes rows >= MH last.
  u16* attf = (u16*)(attn + (size_t)MH * AA);

  // workspace carve-up (~195 MB, within proven footprint)
  char* wp = (char*)d_ws;
  auto take = [&](size_t bytes) { char* p = wp; wp += (bytes + 255) & ~(size_t)255; return p; };
  u16* baf    = (u16*)take((size_t)MT * DD * 2);             // 62.7 MB bf16 (head)
  u8*  baf8   = (u8*)take((size_t)MT * DD);                  // 31.4 MB fp8 (GEMM1 A)
  u8*  baft8  = (u8*)take((size_t)NB * DD * KP);             // 31.7 MB fp8^T (GEMM2 B)
  u8*  attP8  = (u8*)take((size_t)MT * KP);                  // 62.7 MB fp8 scores/attn (full)
  u8*  attwt8 = (u8*)take((size_t)KP * 1408);                // 4.0 MB fp8 (GEMM1 B)
  float* feats = (float*)take((size_t)450560 * 4);           // 1.8 MB
  u16* wt      = (u16*)take((size_t)160 * 2816 * 2);         // 0.9 MB

  conv_k<<<dim3(176), 256, 0, stream>>>(x, conv_w, conv_b, feats);
  gt_k<<<dim3(44, 22, 8), 256, 0, stream>>>(feats, cut_xs, inv, baf, baf8, baft8);
  tr_attw_k<<<dim3(44, 22), 256, 0, stream>>>(attn_w, attwt8);
  wt_k<<<dim3(160), 256, 0, stream>>>(cls_w, reg_w, wt);

  // GEMM1: fp8 scores scattered (+bias) into attP8 (128x128, BK=64, 4 blocks/CU)
  gemm_k<1><<<dim3(174, 22), 512, 0, stream>>>(baf8, attwt8, attP8, nullptr, attn_b);
  // softmax in place over all MT rows; rows<MH also write f32 attn directly
  softf_k<<<dim3(MT), 256, 0, stream>>>(attP8, attn);
  // GEMM2: att_feat = attP8 @ baft8^T, all 8 batches (attf in attn 2nd half)
  gemm_k<2><<<dim3(22, 11, 8), 512, 0, stream>>>(attP8, baft8, nullptr, attf, nullptr);
  // head GEMM (bf16): fused bias + sigmoid + anchors into props
  head_k<<<dim3(174), 256, 0, stream>>>(attf, baf, wt, props,
                                        cls_b, reg_b, anchors);
  // expand rows >= MH to f32 (overwrites attf region - safe, head_k done)
  exp_k<<<dim3(MH), 256, 0, stream>>>(attP8 + (size_t)MH * KP, attn + (size_t)MH * AA);
}

// Round 18
// 600.694 us; speedup vs baseline: 1.0625x; 1.0625x over previous
//
#include <hip/hip_runtime.h>
#include <stdint.h>

typedef __attribute__((ext_vector_type(8))) __bf16 bf16x8;
typedef __attribute__((ext_vector_type(4))) float f32x4;
typedef __attribute__((ext_vector_type(2))) long long2v;
typedef unsigned short u16;
typedef unsigned char u8;

#define DEV static __device__ __forceinline__

constexpr int NB = 8;           // batch
constexpr int AA = 2784;        // anchors
constexpr int AM1 = 2783;       // A-1
constexpr int DD = 1408;        // D = 64*22
constexpr int MT = NB * AA;     // 22272 total rows (= 174*128 exactly)
constexpr int MH = MT / 2;      // first-half rows (f32 attn fused in softmax)
constexpr int KP = 2816;        // padded K / attP row stride (mult of 128)

DEV u16 f2bf(float f) {
  uint32_t u = __builtin_bit_cast(uint32_t, f);
  u += 0x7FFFu + ((u >> 16) & 1u);
  return (u16)(u >> 16);
}
DEV float bf2f(unsigned v) { return __builtin_bit_cast(float, v << 16); }
DEV u8 f2f8(float f) {
  return (u8)(__builtin_amdgcn_cvt_pk_fp8_f32(f, f, 0, false) & 0xff);
}
DEV float4 cv4(unsigned w) {
  float4 r;
  r.x = __builtin_amdgcn_cvt_f32_fp8((int)w, 0);
  r.y = __builtin_amdgcn_cvt_f32_fp8((int)w, 1);
  r.z = __builtin_amdgcn_cvt_f32_fp8((int)w, 2);
  r.w = __builtin_amdgcn_cvt_f32_fp8((int)w, 3);
  return r;
}
DEV unsigned pk4(float a, float b, float c, float d) {
  int r = __builtin_amdgcn_cvt_pk_fp8_f32(a, b, 0, false);
  r = __builtin_amdgcn_cvt_pk_fp8_f32(c, d, r, true);
  return (unsigned)r;
}

// async global->LDS, 16B per lane. LDS dest is wave-uniform base + lane*16 by HW.
DEV void load16_lds(const void* g, void* l) {
  auto gp = (const __attribute__((address_space(1))) uint32_t*)(uintptr_t)g;
  auto lp = (__attribute__((address_space(3))) uint32_t*)(uint32_t)(uintptr_t)l;
  __builtin_amdgcn_global_load_lds(gp, lp, 16, 0, 0);
}

#define VMW(n) asm volatile("s_waitcnt vmcnt(" #n ")" ::: "memory")
#define VMW0 asm volatile("s_waitcnt vmcnt(0)" ::: "memory")
#define LGK(n) asm volatile("s_waitcnt lgkmcnt(" #n ")" ::: "memory")
#define BARR asm volatile("s_barrier" ::: "memory")
#define SCHB __builtin_amdgcn_sched_barrier(0)

// 16 fp8 MFMAs: 4 m-frags x 2 n-frags x 2 k-slots
DEV void mf16c(f32x4 (&acc)[4][2], const long (&a)[4][2], const long (&b)[2][2]) {
  __builtin_amdgcn_s_setprio(1);
#pragma unroll
  for (int mt = 0; mt < 4; ++mt)
#pragma unroll
    for (int nt = 0; nt < 2; ++nt)
#pragma unroll
      for (int ks = 0; ks < 2; ++ks)
        acc[mt][nt] = __builtin_amdgcn_mfma_f32_16x16x32_fp8_fp8(
            a[mt][ks], b[nt][ks], acc[mt][nt], 0, 0, 0);
  __builtin_amdgcn_s_setprio(0);
}

// ------- unified fp8 GEMM (r12-proven): 128x128 tile, 2x4 waves (64x32), BK=128 -------
// 64KB LDS/block -> 2 blocks/CU: cross-block TLP covers wait/barrier bubbles.
// MODE 1: scores = baf8 @ attwt8^T, K=1408 -> scattered fp8 (+bias) into attP8[.][KP]
// MODE 2: att_feat = attP8 @ baft8^T (per batch z), K=2816 -> bf16 out (x1/256)
template <int MODE>
__global__ __launch_bounds__(512, 4) void gemm_k(const u8* __restrict__ A,
                                                 const u8* __restrict__ Bt,
                                                 u8* __restrict__ out8,
                                                 u16* __restrict__ outh,
                                                 const float* __restrict__ bias1) {
  constexpr int K   = (MODE == 1) ? 1408 : KP;
  constexpr int NT  = K / 128;
  constexpr int LDA = (MODE == 1) ? 1408 : KP;
  constexpr int LDB = (MODE == 1) ? 1408 : KP;
  constexpr int MR  = (MODE == 1) ? MT : AA;     // valid A rows
  constexpr int NRB = (MODE == 1) ? KP : 1408;   // valid B rows
  __shared__ __align__(16) u8 As8[2][16384];     // 128 x 128
  __shared__ __align__(16) u8 Bs8[2][16384];     // 128 x 128
  const int tid = threadIdx.x;
  const int lane = tid & 63;
  const int w = tid >> 6;
  const int wr = w >> 2, wc = w & 3;             // wave tile 64 x 32
  const int l16 = lane & 15, lq = lane >> 4;
  const int l7 = l16 & 7;

  // T1 bijective XCD swizzle, y-fastest within chunk
  const int gx = gridDim.x, gy = gridDim.y;
  const int nwg = gx * gy;
  const int i = blockIdx.x + blockIdx.y * gx;
  const int xcd = i & 7, pos = i >> 3;
  const int q = nwg >> 3, r = nwg & 7;
  const int lid = (xcd < r ? xcd * (q + 1) : r * (q + 1) + (xcd - r) * q) + pos;
  const int m0 = (lid / gy) * 128, n0 = (lid % gy) * 128;

  const u8* Ab = A;
  const u8* Bb = Bt;
  u16* outp = outh;
  if constexpr (MODE == 2) {
    const int bz = blockIdx.z;
    Ab += (size_t)bz * AA * KP;
    Bb += (size_t)bz * DD * KP;
    outp += (size_t)bz * AA * DD;
  }

  auto stA = [&](int buf, int kt) {              // 2 insts: 128 rows x 128B
#pragma unroll
    for (int inst = 0; inst < 2; ++inst) {
      int c = tid + inst * 512;
      int row = c >> 3, sl = c & 7;
      int sr = m0 + row;
      sr = sr < MR - 1 ? sr : MR - 1;
      load16_lds(Ab + (size_t)sr * LDA + kt * 128 + ((sl ^ (row & 7)) << 4),
                 &As8[buf][c << 4]);
    }
  };
  auto stB = [&](int buf, int kt) {              // 2 insts: 128 rows x 128B
#pragma unroll
    for (int inst = 0; inst < 2; ++inst) {
      int c = tid + inst * 512;
      int row = c >> 3, sl = c & 7;
      int sr = n0 + row;
      sr = sr < NRB - 1 ? sr : NRB - 1;
      load16_lds(Bb + (size_t)sr * LDB + kt * 128 + ((sl ^ (row & 7)) << 4),
                 &Bs8[buf][c << 4]);
    }
  };
  // b128 fragment reads; XOR slot undoes staging swizzle -> canonical unit kh*4+lq;
  // unit's lo/hi 8B feed the two K=32 MFMAs (k-split consistent between A and B).
  auto rdA = [&](int buf, int kh, long (&a)[4][2]) {
    const int u = (kh * 4 + lq) ^ l7;
#pragma unroll
    for (int mt = 0; mt < 4; ++mt) {
      int rloc = wr * 64 + mt * 16 + l16;
      long2v v = *(const long2v*)&As8[buf][rloc * 128 + u * 16];
      a[mt][0] = v[0]; a[mt][1] = v[1];
    }
  };
  auto rdB = [&](int buf, int kh, long (&b)[2][2]) {
    const int u = (kh * 4 + lq) ^ l7;
#pragma unroll
    for (int nt = 0; nt < 2; ++nt) {
      int R = wc * 32 + nt * 16 + l16;
      long2v v = *(const long2v*)&Bs8[buf][R * 128 + u * 16];
      b[nt][0] = v[0]; b[nt][1] = v[1];
    }
  };

  f32x4 acc[4][2];
#pragma unroll
  for (int i2 = 0; i2 < 4; ++i2)
#pragma unroll
    for (int j = 0; j < 2; ++j) acc[i2][j] = 0.f;

  long a[4][2], bA[2][2], bB[2][2];

  // prologue: buf0 <- t0, buf1 <- t1; wait buf0 (buf1 in flight)
  stA(0, 0); stB(0, 0);
  stA(1, 1); stB(1, 1);
  VMW(4);
  BARR;

  for (int t = 0; t < NT; ++t) {
    const int cur = t & 1, nxt = cur ^ 1;
    // stage t+1 into the buffer whose reads finished at t-1's barrier
    if (t + 1 < NT) { stA(nxt, t + 1); stB(nxt, t + 1); }
    // issue kh0 operands + kh1 B early (in-order DS: count leaves only bB outstanding)
    rdB(cur, 0, bA); rdA(cur, 0, a); rdB(cur, 1, bB);
    LGK(2); SCHB;
    mf16c(acc, a, bA);                 // 16 MFMA; bB reads complete underneath
    rdA(cur, 1, a);
    LGK(0); SCHB;
    mf16c(acc, a, bB);
    if (t + 1 < NT) { VMW0; BARR; }    // staging aged by both MFMA clusters
  }

  // ---- epilogue ----  C/D map: col = lane&15, row = (lane>>4)*4 + reg
  if constexpr (MODE == 1) {
#pragma unroll
    for (int mi = 0; mi < 4; ++mi)
#pragma unroll
      for (int r2 = 0; r2 < 4; ++r2) {
        int m = m0 + wr * 64 + mi * 16 + lq * 4 + r2;   // < MT (174*128 exact)
        int ii = m % AA;
#pragma unroll
        for (int ni = 0; ni < 2; ++ni) {
          int n = n0 + wc * 32 + ni * 16 + l16;
          if (n >= AM1) continue;
          int col = n + (n >= ii);                 // scatter: skip diagonal
          out8[(size_t)m * KP + col] = f2f8(acc[mi][ni][r2] + bias1[n]);
        }
      }
  } else {
#pragma unroll
    for (int mi = 0; mi < 4; ++mi)
#pragma unroll
      for (int r2 = 0; r2 < 4; ++r2) {
        int m = m0 + wr * 64 + mi * 16 + lq * 4 + r2;
        if (m >= AA) continue;
        size_t base = (size_t)m * DD;
#pragma unroll
        for (int ni = 0; ni < 2; ++ni) {
          int n = n0 + wc * 32 + ni * 16 + l16;
          outp[base + n] = f2bf(acc[mi][ni][r2] * 0.00390625f);
        }
      }
  }
}

// ---------------- 1x1 conv: feats[b][o][h][w] ----------------
__global__ __launch_bounds__(256) void conv_k(const float* __restrict__ x,
                                              const float* __restrict__ w,
                                              const float* __restrict__ bias,
                                              float* __restrict__ feats) {
  __shared__ float xs[256 * 40];
  int bb = blockIdx.x / 22, h = blockIdx.x % 22;
  const float* xp = x + (size_t)bb * 256 * 880 + h * 40;
  for (int l = threadIdx.x; l < 256 * 40; l += 256)
    xs[l] = xp[(l / 40) * 880 + (l % 40)];
  __syncthreads();
  for (int l = threadIdx.x; l < 64 * 40; l += 256) {
    int o = l / 40, ww = l % 40;
    float acc = bias[o];
    const float* wr = w + o * 256;
#pragma unroll 8
    for (int c = 0; c < 256; ++c) acc += xs[c * 40 + ww] * wr[c];
    feats[((size_t)(bb * 64 + o) * 22 + h) * 40 + ww] = acc;
  }
}

// ---------------- fused gather+mask -> baf bf16, baf8 fp8, baft8 fp8^T ----------------
__global__ __launch_bounds__(256) void gt_k(const float* __restrict__ feats,
                                            const int* __restrict__ cut,
                                            const u8* __restrict__ inv,
                                            u16* __restrict__ baf,
                                            u8* __restrict__ baf8,
                                            u8* __restrict__ bft8) {
  unsigned probe = 0;
#pragma unroll
  for (int t = 0; t < 10; ++t)
    probe |= (unsigned)inv[4 * t + 1] | (unsigned)inv[4 * t + 2] | (unsigned)inv[4 * t + 3];
  const bool is_u8 = (probe != 0);  // i32 storage -> high bytes all zero
  __shared__ u8 t8[64][65];
  int a0 = blockIdx.x * 64, d0 = blockIdx.y * 64, b = blockIdx.z;
  int tx = threadIdx.x & 63, ty = threadIdx.x >> 6;
  int d = d0 + tx, o = d / 22, h = d - o * 22;
  for (int r = ty; r < 64; r += 4) {
    int a = a0 + r;
    u8 f8 = 0;
    if (a < AA) {
      int msk = is_u8 ? (int)inv[a * 22 + h] : ((const int*)inv)[a * 22 + h];
      float v = 0.f;
      if (!msk) v = feats[((size_t)(b * 64 + o) * 22 + h) * 40 + cut[a * 22 + h]];
      baf[((size_t)b * AA + a) * DD + d] = f2bf(v);
      f8 = f2f8(v);
      baf8[((size_t)b * AA + a) * DD + d] = f8;
    }
    t8[r][tx] = f8;
  }
  __syncthreads();
  for (int r = ty; r < 64; r += 4) {
    int a = a0 + tx;
    if (a < AA) bft8[((size_t)b * DD + d0 + r) * KP + a] = t8[tx][r];
  }
}

// ---------------- attn_w (1408,2783) f32 -> attwt8 (2816,1408) fp8, zero pad ----------------
__global__ __launch_bounds__(256) void tr_attw_k(const float* __restrict__ w,
                                                 u8* __restrict__ wt8) {
  __shared__ u8 t8[64][65];
  int n0 = blockIdx.x * 64, k0 = blockIdx.y * 64;
  int tx = threadIdx.x & 63, ty = threadIdx.x >> 6;
  for (int r = ty; r < 64; r += 4) {
    int n = n0 + tx;
    t8[r][tx] = (n < AM1) ? f2f8(w[(size_t)(k0 + r) * AM1 + n]) : (u8)0;
  }
  __syncthreads();
  for (int r = ty; r < 64; r += 4)
    wt8[(size_t)(n0 + r) * 1408 + k0 + tx] = t8[tx][r];
}

// ---------------- pack head weights bf16: wt[n][k], n<2 cls, 2..145 reg, pad->160 ----------------
__global__ __launch_bounds__(256) void wt_k(const float* __restrict__ cw,
                                            const float* __restrict__ rw,
                                            u16* __restrict__ wt) {
  int n = blockIdx.x;
  for (int k = threadIdx.x; k < 2816; k += 256) {
    float v = 0.f;
    if (n < 2) v = cw[(size_t)k * 2 + n];
    else if (n < 146) v = rw[(size_t)k * 144 + (n - 2)];
    wt[(size_t)n * 2816 + k] = f2bf(v);
  }
}

// ---------------- fp8 row softmax in place; out = attn*256 fp8; rows<MH also write f32 ----------------
__global__ __launch_bounds__(256) void softf_k(u8* __restrict__ attP,
                                               float* __restrict__ fdst) {
  const int row = blockIdx.x;            // 0..MT-1
  const int i = row % AA;
  u8* p = attP + (size_t)row * KP;
  const int t = threadIdx.x;
  const bool act = (t < 176);            // 176 uint4 chunks of 16 fp8
  uint4 qw = act ? ((const uint4*)p)[t] : make_uint4(0, 0, 0, 0);
  float v[16];
  { float4 f = cv4(qw.x); v[0] = f.x; v[1] = f.y; v[2] = f.z; v[3] = f.w; }
  { float4 f = cv4(qw.y); v[4] = f.x; v[5] = f.y; v[6] = f.z; v[7] = f.w; }
  { float4 f = cv4(qw.z); v[8] = f.x; v[9] = f.y; v[10] = f.z; v[11] = f.w; }
  { float4 f = cv4(qw.w); v[12] = f.x; v[13] = f.y; v[14] = f.z; v[15] = f.w; }
  const int base = t * 16;
  float mx = -3e38f;
#pragma unroll
  for (int e = 0; e < 16; ++e) {
    int j = base + e;
    if (act && j < AA && j != i) mx = fmaxf(mx, v[e]);
  }
#pragma unroll
  for (int o = 1; o < 64; o <<= 1) mx = fmaxf(mx, __shfl_xor(mx, o));
  __shared__ float rm[4], rs[4];
  if (!(t & 63)) rm[t >> 6] = mx;
  __syncthreads();
  mx = fmaxf(fmaxf(rm[0], rm[1]), fmaxf(rm[2], rm[3]));
  float s = 0.f, ev[16];
#pragma unroll
  for (int e = 0; e < 16; ++e) {
    int j = base + e;
    float tv = (act && j < AA && j != i) ? __expf(v[e] - mx) : 0.f;
    ev[e] = tv; s += tv;
  }
#pragma unroll
  for (int o = 1; o < 64; o <<= 1) s += __shfl_xor(s, o);
  if (!(t & 63)) rs[t >> 6] = s;
  __syncthreads();
  s = (rs[0] + rs[1]) + (rs[2] + rs[3]);
  const float inv = 1.f / s;
#pragma unroll
  for (int e = 0; e < 16; ++e) ev[e] *= inv;
  if (act) {
    const float sc = 256.f;
    uint4 ow;
    ow.x = pk4(ev[0] * sc, ev[1] * sc, ev[2] * sc, ev[3] * sc);
    ow.y = pk4(ev[4] * sc, ev[5] * sc, ev[6] * sc, ev[7] * sc);
    ow.z = pk4(ev[8] * sc, ev[9] * sc, ev[10] * sc, ev[11] * sc);
    ow.w = pk4(ev[12] * sc, ev[13] * sc, ev[14] * sc, ev[15] * sc);
    ((uint4*)p)[t] = ow;
    // rows < MH: write f32 attn directly (region disjoint from attf park)
    if (row < MH && t < 174) {
      float4* dp = (float4*)(fdst + (size_t)row * AA + base);
      dp[0] = make_float4(ev[0], ev[1], ev[2], ev[3]);
      dp[1] = make_float4(ev[4], ev[5], ev[6], ev[7]);
      dp[2] = make_float4(ev[8], ev[9], ev[10], ev[11]);
      dp[3] = make_float4(ev[12], ev[13], ev[14], ev[15]);
    }
  }
}

// ---------------- fp8*256 (stride KP) -> f32 (stride AA) expand ----------------
__global__ __launch_bounds__(256) void exp_k(const u8* __restrict__ src,
                                             float* __restrict__ dst) {
  int row = blockIdx.x;
  int t = threadIdx.x;
  if (t >= 174) return;
  uint4 qw = ((const uint4*)(src + (size_t)row * KP))[t];
  const float is = 0.00390625f;
  float4 f0 = cv4(qw.x), f1 = cv4(qw.y), f2 = cv4(qw.z), f3 = cv4(qw.w);
  float4* dp = (float4*)(dst + (size_t)row * AA + t * 16);
  dp[0] = make_float4(f0.x * is, f0.y * is, f0.z * is, f0.w * is);
  dp[1] = make_float4(f1.x * is, f1.y * is, f1.z * is, f1.w * is);
  dp[2] = make_float4(f2.x * is, f2.y * is, f2.z * is, f2.w * is);
  dp[3] = make_float4(f3.x * is, f3.y * is, f3.z * is, f3.w * is);
}

// ---------------- head GEMM (bf16, depth-2 counted-vmcnt, BN=160): [attf|baf] @ wt^T ----------------
__global__ __launch_bounds__(256) void head_k(const u16* __restrict__ A1,
                                              const u16* __restrict__ A2,
                                              const u16* __restrict__ Bt,
                                              float* __restrict__ outf,
                                              const float* __restrict__ b1,
                                              const float* __restrict__ b2,
                                              const float* __restrict__ anch) {
  constexpr int K = 2816, NT = K / 32, BN = 160, HN = 80, NF = 5;
  __shared__ __align__(16) u16 As[2][128 * 32];
  __shared__ __align__(16) u16 Bs[2][BN * 32 + 512];   // +1KB pad for clamped overhang
  const int tid = threadIdx.x;
  const int lane = tid & 63;
  const int wm = tid >> 7, wn = (tid >> 6) & 1;
  const int m0 = blockIdx.x * 128;
  const int l16 = lane & 15, lq = lane >> 4;

  // uniform 5 load insts per thread (2 A + 3 B with clamped overhang)
  auto stage = [&](int buf, int t) {
    const int k0 = t * 32;
    const u16* Asrc = (k0 < 1408) ? A1 : A2;
    const int kk = (k0 < 1408) ? k0 : k0 - 1408;
#pragma unroll
    for (int inst = 0; inst < 2; ++inst) {
      int c = tid + inst * 256;
      load16_lds(Asrc + (size_t)(m0 + (c >> 2)) * 1408 + kk + (c & 3) * 8, &As[buf][c * 8]);
    }
#pragma unroll
    for (int inst = 0; inst < 3; ++inst) {
      int c = tid + inst * 256;
      int ce = c < BN * 4 ? c : BN * 4 - 1;
      load16_lds(Bt + (size_t)(ce >> 2) * K + k0 + (ce & 3) * 8, &Bs[buf][ce * 8]);
    }
  };

  f32x4 acc[4][NF];
#pragma unroll
  for (int i = 0; i < 4; ++i)
#pragma unroll
    for (int j = 0; j < NF; ++j) acc[i][j] = 0.f;

  stage(0, 0);
  stage(1, 1);
  for (int t = 0; t < NT; ++t) {
    if (t + 1 < NT) VMW(5); else VMW0;
    BARR;
    const int cur = t & 1;
    bf16x8 av[4], bv[NF];
#pragma unroll
    for (int mt = 0; mt < 4; ++mt)
      av[mt] = *(const bf16x8*)&As[cur][(wm * 64 + mt * 16 + l16) * 32 + lq * 8];
#pragma unroll
    for (int nt = 0; nt < NF; ++nt)
      bv[nt] = *(const bf16x8*)&Bs[cur][(wn * HN + nt * 16 + l16) * 32 + lq * 8];
#pragma unroll
    for (int mt = 0; mt < 4; ++mt)
#pragma unroll
      for (int nt = 0; nt < NF; ++nt)
        acc[mt][nt] = __builtin_amdgcn_mfma_f32_16x16x32_bf16(av[mt], bv[nt], acc[mt][nt], 0, 0, 0);
    BARR;                                 // all waves done reading buf cur
    if (t + 2 < NT) stage(cur, t + 2);
  }

#pragma unroll
  for (int nt = 0; nt < NF; ++nt) {
    int n = wn * HN + nt * 16 + l16;
    if (n >= 146) continue;
#pragma unroll
    for (int mt = 0; mt < 4; ++mt)
#pragma unroll
      for (int r = 0; r < 4; ++r) {
        int m = m0 + wm * 64 + mt * 16 + lq * 4 + r;
        int ii = m % AA;
        float v = acc[mt][nt][r];
        if (n < 2) {
          outf[(size_t)m * 148 + n] = v + b1[n];
          if (n == 0) {
            outf[(size_t)m * 148 + 2] = anch[ii * 148 + 2];
            outf[(size_t)m * 148 + 3] = anch[ii * 148 + 3];
          }
        } else {
          int rr = n - 2;
          v += b2[rr];
          if (rr >= 72) v = 1.f / (1.f + __expf(-v));
          outf[(size_t)m * 148 + 4 + rr] = anch[ii * 148 + 4 + rr] + v;
        }
      }
  }
}

extern "C" void kernel_launch(void* const* d_in, const int* in_sizes, int n_in,
                              void* d_out, int out_size, void* d_ws, size_t ws_size,
                              hipStream_t stream) {
  const float* x       = (const float*)d_in[0];
  const float* conv_w  = (const float*)d_in[1];
  const float* conv_b  = (const float*)d_in[2];
  const float* attn_w  = (const float*)d_in[3];
  const float* attn_b  = (const float*)d_in[4];
  const float* cls_w   = (const float*)d_in[5];
  const float* cls_b   = (const float*)d_in[6];
  const float* reg_w   = (const float*)d_in[7];
  const float* reg_b   = (const float*)d_in[8];
  const float* anchors = (const float*)d_in[9];
  const int*   cut_xs  = (const int*)d_in[10];
  const u8*    inv     = (const u8*)d_in[11];

  float* props = (float*)d_out;
  float* attn  = props + (size_t)MT * 148;   // f32 attn_mat out (248 MB)
  // attf (62.7 MB) parks in the SECOND half of attn [MH rows onward]; softmax
  // writes f32 rows < MH directly (disjoint); exp_k finishes rows >= MH last.
  u16* attf = (u16*)(attn + (size_t)MH * AA);

  // workspace carve-up (~195 MB, within proven footprint)
  char* wp = (char*)d_ws;
  auto take = [&](size_t bytes) { char* p = wp; wp += (bytes + 255) & ~(size_t)255; return p; };
  u16* baf    = (u16*)take((size_t)MT * DD * 2);             // 62.7 MB bf16 (head)
  u8*  baf8   = (u8*)take((size_t)MT * DD);                  // 31.4 MB fp8 (GEMM1 A)
  u8*  baft8  = (u8*)take((size_t)NB * DD * KP);             // 31.7 MB fp8^T (GEMM2 B)
  u8*  attP8  = (u8*)take((size_t)MT * KP);                  // 62.7 MB fp8 scores/attn (full)
  u8*  attwt8 = (u8*)take((size_t)KP * 1408);                // 4.0 MB fp8 (GEMM1 B)
  float* feats = (float*)take((size_t)450560 * 4);           // 1.8 MB
  u16* wt      = (u16*)take((size_t)160 * 2816 * 2);         // 0.9 MB

  conv_k<<<dim3(176), 256, 0, stream>>>(x, conv_w, conv_b, feats);
  gt_k<<<dim3(44, 22, 8), 256, 0, stream>>>(feats, cut_xs, inv, baf, baf8, baft8);
  tr_attw_k<<<dim3(44, 22), 256, 0, stream>>>(attn_w, attwt8);
  wt_k<<<dim3(160), 256, 0, stream>>>(cls_w, reg_w, wt);

  // GEMM1: fp8 scores scattered (+bias) into attP8 (128x128, 2 blocks/CU)
  gemm_k<1><<<dim3(174, 22), 512, 0, stream>>>(baf8, attwt8, attP8, nullptr, attn_b);
  // softmax in place over all MT rows; rows<MH also write f32 attn directly
  softf_k<<<dim3(MT), 256, 0, stream>>>(attP8, attn);
  // GEMM2: att_feat = attP8 @ baft8^T, all 8 batches (attf in attn 2nd half)
  gemm_k<2><<<dim3(22, 11, 8), 512, 0, stream>>>(attP8, baft8, nullptr, attf, nullptr);
  // head GEMM (bf16): fused bias + sigmoid + anchors into props
  head_k<<<dim3(174), 256, 0, stream>>>(attf, baf, wt, props,
                                        cls_b, reg_b, anchors);
  // expand rows >= MH to f32 (overwrites attf region - safe, head_k done)
  exp_k<<<dim3(MH), 256, 0, stream>>>(attP8 + (size_t)MH * KP, attn + (size_t)MH * AA);
}